// Round 3
// baseline (444.521 us; speedup 1.0000x reference)
//
#include <hip/hip_runtime.h>
#include <hip/hip_bf16.h>
#include <stdint.h>

#define S_LEN 2688
#define DIM   1536
#define NH    12
#define HD    128
#define QKV_N 4608   // 3*DIM

typedef __attribute__((ext_vector_type(8))) short bf16x8;
typedef __attribute__((ext_vector_type(4))) float f32x4;

__device__ inline ushort f2bf(float f) {
    uint32_t u = __float_as_uint(f);
    uint32_t r = (u + 0x7fffu + ((u >> 16) & 1u)) >> 16;
    return (ushort)r;
}

#define GLOAD16(gp, lp) __builtin_amdgcn_global_load_lds( \
    (__attribute__((address_space(1))) const void*)(gp),  \
    (__attribute__((address_space(3))) void*)(lp), 16, 0, 0)

// ---------------------------------------------------------------------------
// 1) fp32 -> bf16 convert: x and the four weight matrices (fused into wb)
// ---------------------------------------------------------------------------
__global__ __launch_bounds__(256) void convert_all(
    const float* __restrict__ x,
    const float* __restrict__ wq, const float* __restrict__ wk,
    const float* __restrict__ wv, const float* __restrict__ wo,
    ushort* __restrict__ xb, ushort* __restrict__ wb)
{
    const size_t NX4 = (size_t)S_LEN * DIM / 4;   // 1,032,192
    const size_t NW4 = (size_t)DIM * DIM / 4;     //   589,824
    size_t i = (size_t)blockIdx.x * 256 + threadIdx.x;
    const float* src; ushort* dst;
    if (i < NX4)            { src = x;  dst = xb; }
    else if (i < NX4+1*NW4) { src = wq; dst = wb;                        i -= NX4; }
    else if (i < NX4+2*NW4) { src = wk; dst = wb + 1*(size_t)DIM*DIM;    i -= NX4+1*NW4; }
    else if (i < NX4+3*NW4) { src = wv; dst = wb + 2*(size_t)DIM*DIM;    i -= NX4+2*NW4; }
    else if (i < NX4+4*NW4) { src = wo; dst = wb + 3*(size_t)DIM*DIM;    i -= NX4+3*NW4; }
    else return;
    float4 v = reinterpret_cast<const float4*>(src)[i];
    ushort4 o = { f2bf(v.x), f2bf(v.y), f2bf(v.z), f2bf(v.w) };
    reinterpret_cast<ushort4*>(dst)[i] = o;
}

// ---------------------------------------------------------------------------
// 2) bf16 GEMM, B^T layout: C[m][n] = sum_k A[m][k]*B[n][k] + bias[n]
//    128x128 tile, BK=64, 4 waves (2x2), 16x16x32 MFMA, global_load_lds w=16
// ---------------------------------------------------------------------------
__global__ __launch_bounds__(256) void gemm_bt(
    const ushort* __restrict__ A, const ushort* __restrict__ B,
    const float* __restrict__ b0, const float* __restrict__ b1,
    const float* __restrict__ b2,
    float* __restrict__ C, int M, int N, int K)
{
    __shared__ ushort At[128 * 64];
    __shared__ ushort Bt[128 * 64];
    const int tid  = threadIdx.x;
    const int wave = tid >> 6, lane = tid & 63;
    const int m0 = blockIdx.x * 128, n0 = blockIdx.y * 128;
    const int wr = wave >> 1, wc = wave & 1;
    const int r = lane & 15, g = lane >> 4;
    const int srow = wave * 8 + (lane >> 3);   // staging row within 32-row chunk
    const int scol = (lane & 7) * 8;           // staging col (8 bf16 = 16B)

    f32x4 acc[4][4] = {};

    for (int k0 = 0; k0 < K; k0 += 64) {
        const ushort* Ag = A + (size_t)m0 * K + k0;
        const ushort* Bg = B + (size_t)n0 * K + k0;
#pragma unroll
        for (int t = 0; t < 4; ++t) {
            GLOAD16(Ag + (size_t)(t*32 + srow) * K + scol, &At[t*2048 + wave*512]);
            GLOAD16(Bg + (size_t)(t*32 + srow) * K + scol, &Bt[t*2048 + wave*512]);
        }
        asm volatile("s_waitcnt vmcnt(0)" ::: "memory");
        __syncthreads();
#pragma unroll
        for (int kk = 0; kk < 2; ++kk) {
            bf16x8 af[4], bfr[4];
#pragma unroll
            for (int i = 0; i < 4; ++i)
                af[i] = *reinterpret_cast<const bf16x8*>(
                    &At[(wr*64 + i*16 + r) * 64 + kk*32 + g*8]);
#pragma unroll
            for (int i = 0; i < 4; ++i)
                bfr[i] = *reinterpret_cast<const bf16x8*>(
                    &Bt[(wc*64 + i*16 + r) * 64 + kk*32 + g*8]);
#pragma unroll
            for (int mi = 0; mi < 4; ++mi)
#pragma unroll
                for (int ni = 0; ni < 4; ++ni)
                    acc[mi][ni] = __builtin_amdgcn_mfma_f32_16x16x32_bf16(
                        af[mi], bfr[ni], acc[mi][ni], 0, 0, 0);
        }
        __syncthreads();
    }

#pragma unroll
    for (int ni = 0; ni < 4; ++ni) {
        int col = n0 + wc*64 + ni*16 + r;
        float bias = (col < DIM) ? b0[col]
                   : (col < 2*DIM) ? b1[col - DIM] : b2[col - 2*DIM];
#pragma unroll
        for (int mi = 0; mi < 4; ++mi) {
            int row = m0 + wr*64 + mi*16 + g*4;
#pragma unroll
            for (int j = 0; j < 4; ++j)
                C[(size_t)(row + j) * N + col] = acc[mi][ni][j] + bias;
        }
    }
}

// ---------------------------------------------------------------------------
// 3) RMS-norm + RoPE for q,k; writes head-major bf16 [n][s][d].
//    1/sqrt(D) attention scale folded into q.
// ---------------------------------------------------------------------------
__global__ __launch_bounds__(256) void normrope(
    const float* __restrict__ qkv, const int* __restrict__ gsz,
    const float* __restrict__ gq, const float* __restrict__ gk,
    const float* __restrict__ fcos, const float* __restrict__ fsin,
    ushort* __restrict__ q_r, ushort* __restrict__ k_r)
{
    const int s   = blockIdx.x;
    const int tid = threadIdx.x;
    const int wave = tid >> 6, lane = tid & 63;
    const float2* qrow = reinterpret_cast<const float2*>(qkv + (size_t)s * QKV_N);
    const float2* krow = reinterpret_cast<const float2*>(qkv + (size_t)s * QKV_N + DIM);

    float2 qv[3], kv[3];
    float sq = 0.f, sk = 0.f;
#pragma unroll
    for (int i = 0; i < 3; ++i) {
        int p = tid + i*256;
        qv[i] = qrow[p]; kv[i] = krow[p];
        sq += qv[i].x*qv[i].x + qv[i].y*qv[i].y;
        sk += kv[i].x*kv[i].x + kv[i].y*kv[i].y;
    }
#pragma unroll
    for (int off = 1; off < 64; off <<= 1) {
        sq += __shfl_xor(sq, off);
        sk += __shfl_xor(sk, off);
    }
    __shared__ float red[4][2];
    if (lane == 0) { red[wave][0] = sq; red[wave][1] = sk; }
    __syncthreads();
    sq = red[0][0] + red[1][0] + red[2][0] + red[3][0];
    sk = red[0][1] + red[1][1] + red[2][1] + red[3][1];
    const float rmsq = rsqrtf(sq * (1.f/DIM) + 1e-6f);
    const float rmsk = rsqrtf(sk * (1.f/DIM) + 1e-6f);

    const int hh = gsz[1], ww = gsz[2];
    const int fidx = s / (hh*ww), rem = s % (hh*ww);
    const int hidx = rem / ww,  widx = rem % ww;
    const float qscale = rmsq * 0.08838834764831845f;  // fold 1/sqrt(128)

#pragma unroll
    for (int i = 0; i < 3; ++i) {
        int p = tid + i*256;               // pair index 0..767
        int c = p & 63, head = p >> 6;
        int coord = (c < 22) ? fidx : (c < 43) ? hidx : widx;
        float cv = fcos[coord*64 + c], sv = fsin[coord*64 + c];
        float2 gqv = reinterpret_cast<const float2*>(gq)[p];
        float2 gkv = reinterpret_cast<const float2*>(gk)[p];
        float a = qv[i].x * qscale * gqv.x, b = qv[i].y * qscale * gqv.y;
        ushort2 qo = { f2bf(a*cv - b*sv), f2bf(a*sv + b*cv) };
        a = kv[i].x * rmsk * gkv.x; b = kv[i].y * rmsk * gkv.y;
        ushort2 ko = { f2bf(a*cv - b*sv), f2bf(a*sv + b*cv) };
        size_t off = ((size_t)head * S_LEN + s) * HD + 2*c;
        *reinterpret_cast<ushort2*>(q_r + off) = qo;
        *reinterpret_cast<ushort2*>(k_r + off) = ko;
    }
}

// ---------------------------------------------------------------------------
// 4) V: fp32 [s][3*DIM..] slice -> bf16 transposed [n][d][s] via LDS tile
// ---------------------------------------------------------------------------
__global__ __launch_bounds__(256) void vtrans(
    const float* __restrict__ qkv, ushort* __restrict__ v_t)
{
    __shared__ ushort tile[32][33];
    const int s0 = blockIdx.x * 32;
    const int d0 = blockIdx.y * 32;     // within 1536
    const int tid = threadIdx.x;
#pragma unroll
    for (int e = 0; e < 4; ++e) {
        int idx = tid + e*256;
        int sl = idx >> 5, dl = idx & 31;
        tile[dl][sl] = f2bf(qkv[(size_t)(s0+sl) * QKV_N + 2*DIM + d0 + dl]);
    }
    __syncthreads();
#pragma unroll
    for (int e = 0; e < 4; ++e) {
        int idx = tid + e*256;
        int dl = idx >> 5, sl = idx & 31;
        int d = d0 + dl;
        int head = d >> 7, dd = d & 127;
        v_t[((size_t)head * HD + dd) * S_LEN + s0 + sl] = tile[dl][sl];
    }
}

// ---------------------------------------------------------------------------
// 5) Flash attention: 1 wave per 16-row Q tile, online softmax.
//    scores frag D-layout: row(q)=4*(lane>>4)+reg, col(k)=lane&15  [m89]
// ---------------------------------------------------------------------------
__global__ __launch_bounds__(256) void attn_fwd(
    const ushort* __restrict__ q_r, const ushort* __restrict__ k_r,
    const ushort* __restrict__ v_t, const int* __restrict__ seq_lens,
    ushort* __restrict__ attn_out)
{
    __shared__ ushort Pl[4][16 * 40];   // per-wave P buffer, padded stride 40
    const int tid  = threadIdx.x;
    const int wave = tid >> 6, lane = tid & 63;
    const int n  = blockIdx.y;
    const int q0 = (blockIdx.x * 4 + wave) * 16;
    const int seq = seq_lens[0];
    const int r = lane & 15, g = lane >> 4;
    const ushort* Qh = q_r + (size_t)n * S_LEN * HD;
    const ushort* Kh = k_r + (size_t)n * S_LEN * HD;
    const ushort* Vh = v_t + (size_t)n * HD * S_LEN;

    bf16x8 qf[4];
#pragma unroll
    for (int c = 0; c < 4; ++c)
        qf[c] = *reinterpret_cast<const bf16x8*>(Qh + (size_t)(q0 + r) * HD + c*32 + g*8);

    f32x4 oacc[8] = {};
    float mrun[4] = {-1e30f, -1e30f, -1e30f, -1e30f};
    float lrun[4] = {0.f, 0.f, 0.f, 0.f};

    const int ntiles = (seq + 31) >> 5;
    for (int kt = 0; kt < ntiles; ++kt) {
        const int k0 = kt * 32;
        f32x4 sf[2];
#pragma unroll
        for (int kb = 0; kb < 2; ++kb) {
            f32x4 s = {0.f, 0.f, 0.f, 0.f};
            const int krow = k0 + kb*16 + r;
            const ushort* kp = Kh + (size_t)krow * HD + g*8;
#pragma unroll
            for (int c = 0; c < 4; ++c)
                s = __builtin_amdgcn_mfma_f32_16x16x32_bf16(
                    qf[c], *reinterpret_cast<const bf16x8*>(kp + c*32), s, 0, 0, 0);
            if (krow >= seq) { s[0] = -1e30f; s[1] = -1e30f; s[2] = -1e30f; s[3] = -1e30f; }
            sf[kb] = s;
        }
        // ---- online softmax over 32 key cols (rows live in 16-lane groups)
        float pm[4], scl[4], ps[4];
#pragma unroll
        for (int j = 0; j < 4; ++j) pm[j] = fmaxf(sf[0][j], sf[1][j]);
#pragma unroll
        for (int off = 1; off < 16; off <<= 1)
#pragma unroll
            for (int j = 0; j < 4; ++j) pm[j] = fmaxf(pm[j], __shfl_xor(pm[j], off));
#pragma unroll
        for (int j = 0; j < 4; ++j) {
            float mn = fmaxf(mrun[j], pm[j]);
            scl[j] = __expf(mrun[j] - mn);
            mrun[j] = mn;
        }
#pragma unroll
        for (int j = 0; j < 4; ++j) {
            sf[0][j] = __expf(sf[0][j] - mrun[j]);
            sf[1][j] = __expf(sf[1][j] - mrun[j]);
            ps[j] = sf[0][j] + sf[1][j];
        }
#pragma unroll
        for (int off = 1; off < 16; off <<= 1)
#pragma unroll
            for (int j = 0; j < 4; ++j) ps[j] += __shfl_xor(ps[j], off);
#pragma unroll
        for (int j = 0; j < 4; ++j) lrun[j] = lrun[j] * scl[j] + ps[j];
#pragma unroll
        for (int f = 0; f < 8; ++f)
#pragma unroll
            for (int j = 0; j < 4; ++j) oacc[f][j] *= scl[j];
        // ---- P -> LDS (bf16), re-read as MFMA A-fragment
#pragma unroll
        for (int kb = 0; kb < 2; ++kb)
#pragma unroll
            for (int j = 0; j < 4; ++j)
                Pl[wave][(g*4 + j)*40 + kb*16 + r] = f2bf(sf[kb][j]);
        bf16x8 pf = *reinterpret_cast<const bf16x8*>(&Pl[wave][r*40 + g*8]);
        // ---- PV: V fragments contiguous thanks to [n][d][s] layout
#pragma unroll
        for (int db = 0; db < 8; ++db) {
            bf16x8 vf = *reinterpret_cast<const bf16x8*>(
                Vh + (size_t)(db*16 + r) * S_LEN + k0 + g*8);
            oacc[db] = __builtin_amdgcn_mfma_f32_16x16x32_bf16(pf, vf, oacc[db], 0, 0, 0);
        }
    }

    float inv[4];
#pragma unroll
    for (int j = 0; j < 4; ++j) inv[j] = (lrun[j] > 0.f) ? 1.f / lrun[j] : 0.f;
#pragma unroll
    for (int db = 0; db < 8; ++db)
#pragma unroll
        for (int j = 0; j < 4; ++j)
            attn_out[(size_t)(q0 + g*4 + j) * DIM + n*HD + db*16 + r] =
                f2bf(oacc[db][j] * inv[j]);
}

// ---------------------------------------------------------------------------
extern "C" void kernel_launch(void* const* d_in, const int* in_sizes, int n_in,
                              void* d_out, int out_size, void* d_ws, size_t ws_size,
                              hipStream_t stream)
{
    const float* x    = (const float*)d_in[0];
    const int*   seqL = (const int*)  d_in[1];
    const int*   gsz  = (const int*)  d_in[2];
    const float* fcos = (const float*)d_in[3];
    const float* fsin = (const float*)d_in[4];
    const float* Wq   = (const float*)d_in[5];
    const float* bq   = (const float*)d_in[6];
    const float* Wk   = (const float*)d_in[7];
    const float* bk   = (const float*)d_in[8];
    const float* Wv   = (const float*)d_in[9];
    const float* bv   = (const float*)d_in[10];
    const float* Wo   = (const float*)d_in[11];
    const float* bo   = (const float*)d_in[12];
    const float* gq   = (const float*)d_in[13];
    const float* gk   = (const float*)d_in[14];
    float* out = (float*)d_out;

    char* ws = (char*)d_ws;
    ushort* xb  = (ushort*)ws;                               // 8,257,536 B
    ushort* wb  = xb + (size_t)S_LEN * DIM;                  // 18,874,368 B
    float*  qkv = (float*)(wb + 4*(size_t)DIM*DIM);          // 49,545,216 B
    ushort* q_r = (ushort*)((char*)qkv + (size_t)S_LEN*QKV_N*4); // 8,257,536 B
    ushort* k_r = q_r + (size_t)S_LEN * DIM;                 // 8,257,536 B
    ushort* v_t = k_r + (size_t)S_LEN * DIM;                 // 8,257,536 B
    ushort* ao  = v_t + (size_t)S_LEN * DIM;                 // 8,257,536 B
    // total ws use: ~109.7 MB

    convert_all<<<13248, 256, 0, stream>>>(x, Wq, Wk, Wv, Wo, xb, wb);
    gemm_bt<<<dim3(21, 36), 256, 0, stream>>>(xb, wb, bq, bk, bv, qkv,
                                              S_LEN, QKV_N, DIM);
    normrope<<<S_LEN, 256, 0, stream>>>(qkv, gsz, gq, gk, fcos, fsin, q_r, k_r);
    vtrans<<<dim3(84, 48), 256, 0, stream>>>(qkv, v_t);
    attn_fwd<<<dim3(42, 12), 256, 0, stream>>>(q_r, k_r, v_t, seqL, ao);
    gemm_bt<<<dim3(21, 12), 256, 0, stream>>>(ao, wb + 3*(size_t)DIM*DIM,
                                              bo, bo, bo, out,
                                              S_LEN, DIM, DIM);
}

// Round 5
// 263.901 us; speedup vs baseline: 1.6844x; 1.6844x over previous
//
#include <hip/hip_runtime.h>
#include <hip/hip_bf16.h>
#include <stdint.h>

#define S_LEN 2688
#define DIM   1536
#define NH    12
#define HD    128
#define QKV_N 4608   // 3*DIM

typedef __attribute__((ext_vector_type(8))) short bf16x8;
typedef __attribute__((ext_vector_type(4))) float f32x4;

__device__ inline ushort f2bf(float f) {
    uint32_t u = __float_as_uint(f);
    uint32_t r = (u + 0x7fffu + ((u >> 16) & 1u)) >> 16;
    return (ushort)r;
}

#define GLOAD16(gp, lp) __builtin_amdgcn_global_load_lds( \
    (__attribute__((address_space(1))) const void*)(gp),  \
    (__attribute__((address_space(3))) void*)(lp), 16, 0, 0)

// ---------------------------------------------------------------------------
// 1) fp32 -> bf16 convert: x and the four weight matrices (fused into wb)
// ---------------------------------------------------------------------------
__global__ __launch_bounds__(256) void convert_all(
    const float* __restrict__ x,
    const float* __restrict__ wq, const float* __restrict__ wk,
    const float* __restrict__ wv, const float* __restrict__ wo,
    ushort* __restrict__ xb, ushort* __restrict__ wb)
{
    const size_t NX4 = (size_t)S_LEN * DIM / 4;   // 1,032,192
    const size_t NW4 = (size_t)DIM * DIM / 4;     //   589,824
    size_t i = (size_t)blockIdx.x * 256 + threadIdx.x;
    const float* src; ushort* dst;
    if (i < NX4)            { src = x;  dst = xb; }
    else if (i < NX4+1*NW4) { src = wq; dst = wb;                        i -= NX4; }
    else if (i < NX4+2*NW4) { src = wk; dst = wb + 1*(size_t)DIM*DIM;    i -= NX4+1*NW4; }
    else if (i < NX4+3*NW4) { src = wv; dst = wb + 2*(size_t)DIM*DIM;    i -= NX4+2*NW4; }
    else if (i < NX4+4*NW4) { src = wo; dst = wb + 3*(size_t)DIM*DIM;    i -= NX4+3*NW4; }
    else return;
    float4 v = reinterpret_cast<const float4*>(src)[i];
    ushort4 o = { f2bf(v.x), f2bf(v.y), f2bf(v.z), f2bf(v.w) };
    reinterpret_cast<ushort4*>(dst)[i] = o;
}

// ---------------------------------------------------------------------------
// 2) bf16 GEMM, B^T layout: C[m][n] = sum_k A[m][k]*B[n][k] + bias[n]
//    128x128 tile, BK=64, 4 waves (2x2), 16x16x32 MFMA, global_load_lds w=16
// ---------------------------------------------------------------------------
__global__ __launch_bounds__(256) void gemm_bt(
    const ushort* __restrict__ A, const ushort* __restrict__ B,
    const float* __restrict__ b0, const float* __restrict__ b1,
    const float* __restrict__ b2,
    float* __restrict__ C, int M, int N, int K)
{
    __shared__ ushort At[128 * 64];
    __shared__ ushort Bt[128 * 64];
    const int tid  = threadIdx.x;
    const int wave = tid >> 6, lane = tid & 63;
    const int m0 = blockIdx.x * 128, n0 = blockIdx.y * 128;
    const int wr = wave >> 1, wc = wave & 1;
    const int r = lane & 15, g = lane >> 4;
    const int srow = wave * 8 + (lane >> 3);   // staging row within 32-row chunk
    const int scol = (lane & 7) * 8;           // staging col (8 bf16 = 16B)

    f32x4 acc[4][4] = {};

    for (int k0 = 0; k0 < K; k0 += 64) {
        const ushort* Ag = A + (size_t)m0 * K + k0;
        const ushort* Bg = B + (size_t)n0 * K + k0;
#pragma unroll
        for (int t = 0; t < 4; ++t) {
            GLOAD16(Ag + (size_t)(t*32 + srow) * K + scol, &At[t*2048 + wave*512]);
            GLOAD16(Bg + (size_t)(t*32 + srow) * K + scol, &Bt[t*2048 + wave*512]);
        }
        asm volatile("s_waitcnt vmcnt(0)" ::: "memory");
        __syncthreads();
#pragma unroll
        for (int kk = 0; kk < 2; ++kk) {
            bf16x8 af[4], bfr[4];
#pragma unroll
            for (int i = 0; i < 4; ++i)
                af[i] = *reinterpret_cast<const bf16x8*>(
                    &At[(wr*64 + i*16 + r) * 64 + kk*32 + g*8]);
#pragma unroll
            for (int i = 0; i < 4; ++i)
                bfr[i] = *reinterpret_cast<const bf16x8*>(
                    &Bt[(wc*64 + i*16 + r) * 64 + kk*32 + g*8]);
#pragma unroll
            for (int mi = 0; mi < 4; ++mi)
#pragma unroll
                for (int ni = 0; ni < 4; ++ni)
                    acc[mi][ni] = __builtin_amdgcn_mfma_f32_16x16x32_bf16(
                        af[mi], bfr[ni], acc[mi][ni], 0, 0, 0);
        }
        __syncthreads();
    }

#pragma unroll
    for (int ni = 0; ni < 4; ++ni) {
        int col = n0 + wc*64 + ni*16 + r;
        float bias = (col < DIM) ? b0[col]
                   : (col < 2*DIM) ? b1[col - DIM] : b2[col - 2*DIM];
#pragma unroll
        for (int mi = 0; mi < 4; ++mi) {
            int row = m0 + wr*64 + mi*16 + g*4;
#pragma unroll
            for (int j = 0; j < 4; ++j)
                C[(size_t)(row + j) * N + col] = acc[mi][ni][j] + bias;
        }
    }
}

// ---------------------------------------------------------------------------
// 3) RMS-norm + RoPE for q,k; writes head-major bf16 [n][s][d].
//    1/sqrt(D) attention scale folded into q.
// ---------------------------------------------------------------------------
__global__ __launch_bounds__(256) void normrope(
    const float* __restrict__ qkv, const int* __restrict__ gsz,
    const float* __restrict__ gq, const float* __restrict__ gk,
    const float* __restrict__ fcos, const float* __restrict__ fsin,
    ushort* __restrict__ q_r, ushort* __restrict__ k_r)
{
    const int s   = blockIdx.x;
    const int tid = threadIdx.x;
    const int wave = tid >> 6, lane = tid & 63;
    const float2* qrow = reinterpret_cast<const float2*>(qkv + (size_t)s * QKV_N);
    const float2* krow = reinterpret_cast<const float2*>(qkv + (size_t)s * QKV_N + DIM);

    float2 qv[3], kv[3];
    float sq = 0.f, sk = 0.f;
#pragma unroll
    for (int i = 0; i < 3; ++i) {
        int p = tid + i*256;
        qv[i] = qrow[p]; kv[i] = krow[p];
        sq += qv[i].x*qv[i].x + qv[i].y*qv[i].y;
        sk += kv[i].x*kv[i].x + kv[i].y*kv[i].y;
    }
#pragma unroll
    for (int off = 1; off < 64; off <<= 1) {
        sq += __shfl_xor(sq, off);
        sk += __shfl_xor(sk, off);
    }
    __shared__ float red[4][2];
    if (lane == 0) { red[wave][0] = sq; red[wave][1] = sk; }
    __syncthreads();
    sq = red[0][0] + red[1][0] + red[2][0] + red[3][0];
    sk = red[0][1] + red[1][1] + red[2][1] + red[3][1];
    const float rmsq = rsqrtf(sq * (1.f/DIM) + 1e-6f);
    const float rmsk = rsqrtf(sk * (1.f/DIM) + 1e-6f);

    const int hh = gsz[1], ww = gsz[2];
    const int fidx = s / (hh*ww), rem = s % (hh*ww);
    const int hidx = rem / ww,  widx = rem % ww;
    const float qscale = rmsq * 0.08838834764831845f;  // fold 1/sqrt(128)

#pragma unroll
    for (int i = 0; i < 3; ++i) {
        int p = tid + i*256;               // pair index 0..767
        int c = p & 63, head = p >> 6;
        int coord = (c < 22) ? fidx : (c < 43) ? hidx : widx;
        float cv = fcos[coord*64 + c], sv = fsin[coord*64 + c];
        float2 gqv = reinterpret_cast<const float2*>(gq)[p];
        float2 gkv = reinterpret_cast<const float2*>(gk)[p];
        float a = qv[i].x * qscale * gqv.x, b = qv[i].y * qscale * gqv.y;
        ushort2 qo = { f2bf(a*cv - b*sv), f2bf(a*sv + b*cv) };
        a = kv[i].x * rmsk * gkv.x; b = kv[i].y * rmsk * gkv.y;
        ushort2 ko = { f2bf(a*cv - b*sv), f2bf(a*sv + b*cv) };
        size_t off = ((size_t)head * S_LEN + s) * HD + 2*c;
        *reinterpret_cast<ushort2*>(q_r + off) = qo;
        *reinterpret_cast<ushort2*>(k_r + off) = ko;
    }
}

// ---------------------------------------------------------------------------
// 4) V: fp32 [s][3*DIM..] slice -> bf16 transposed [n][d][s] via LDS tile
// ---------------------------------------------------------------------------
__global__ __launch_bounds__(256) void vtrans(
    const float* __restrict__ qkv, ushort* __restrict__ v_t)
{
    __shared__ ushort tile[32][33];
    const int s0 = blockIdx.x * 32;
    const int d0 = blockIdx.y * 32;     // within 1536
    const int tid = threadIdx.x;
#pragma unroll
    for (int e = 0; e < 4; ++e) {
        int idx = tid + e*256;
        int sl = idx >> 5, dl = idx & 31;
        tile[dl][sl] = f2bf(qkv[(size_t)(s0+sl) * QKV_N + 2*DIM + d0 + dl]);
    }
    __syncthreads();
#pragma unroll
    for (int e = 0; e < 4; ++e) {
        int idx = tid + e*256;
        int dl = idx >> 5, sl = idx & 31;
        int d = d0 + dl;
        int head = d >> 7, dd = d & 127;
        v_t[((size_t)head * HD + dd) * S_LEN + s0 + sl] = tile[dl][sl];
    }
}

// ---------------------------------------------------------------------------
// 5) Flash attention, LDS-staged: 4 waves/block share one head.
//    KVBLK=64, double-buffered global_load_lds staging with both-sides
//    XOR chunk swizzle (rule #21): global source chunk w^=(row&7) at stage,
//    read chunk ^= (r&7). Per-wave 16 Q rows; online softmax.
//    scores frag D-layout: row(q)=4*(lane>>4)+reg, col(k)=lane&15  [m89]
// ---------------------------------------------------------------------------
__global__ __launch_bounds__(256) void attn_fwd(
    const ushort* __restrict__ q_r, const ushort* __restrict__ k_r,
    const ushort* __restrict__ v_t, const int* __restrict__ seq_lens,
    ushort* __restrict__ attn_out)
{
    __shared__ ushort Kl[2][64 * 128];   // 2 x 16 KB, [row 0..63][chunk swz]
    __shared__ ushort Vl[2][128 * 64];   // 2 x 16 KB, [d 0..127][chunk swz]
    __shared__ ushort Pl[4][16 * 72];    // per-wave P, stride 72
    const int tid  = threadIdx.x;
    const int wave = tid >> 6, lane = tid & 63;
    const int n  = blockIdx.y;
    const int q0 = blockIdx.x * 64 + wave * 16;
    const int seq = seq_lens[0];
    const int r = lane & 15, g = lane >> 4;
    const int swz = r & 7;
    const ushort* Qh = q_r + (size_t)n * S_LEN * HD;
    const ushort* Kh = k_r + (size_t)n * S_LEN * HD;
    const ushort* Vh = v_t + (size_t)n * HD * S_LEN;

    // staging indices (per thread): K chunk j = t*256+tid
    const int kj_row[4] = { (0*256+tid)>>4, (1*256+tid)>>4, (2*256+tid)>>4, (3*256+tid)>>4 };
    const int kj_w  = tid & 15;
    const int vj_d[4]  = { (0*256+tid)>>3, (1*256+tid)>>3, (2*256+tid)>>3, (3*256+tid)>>3 };
    const int vj_w  = tid & 7;

    bf16x8 qf[4];
#pragma unroll
    for (int c = 0; c < 4; ++c)
        qf[c] = *reinterpret_cast<const bf16x8*>(Qh + (size_t)(q0 + r) * HD + c*32 + g*8);

    f32x4 oacc[8] = {};
    float mrun[4] = {-1e30f, -1e30f, -1e30f, -1e30f};
    float lrun[4] = {0.f, 0.f, 0.f, 0.f};

    const int nt = (seq + 63) >> 6;

#define STAGE(buf, kbase)                                                     \
    do {                                                                      \
        _Pragma("unroll")                                                     \
        for (int t = 0; t < 4; ++t) {                                         \
            int row = kj_row[t];                                              \
            GLOAD16(Kh + (size_t)((kbase) + row) * HD + ((kj_w ^ (row & 7)) * 8), \
                    &Kl[buf][(t*256 + wave*64) * 8]);                         \
        }                                                                     \
        _Pragma("unroll")                                                     \
        for (int t = 0; t < 4; ++t) {                                         \
            int d = vj_d[t];                                                  \
            GLOAD16(Vh + (size_t)d * S_LEN + (kbase) + ((vj_w ^ (d & 7)) * 8), \
                    &Vl[buf][(t*256 + wave*64) * 8]);                         \
        }                                                                     \
    } while (0)

    STAGE(0, 0);
    asm volatile("s_waitcnt vmcnt(0)" ::: "memory");
    __syncthreads();

    int cur = 0;
    for (int kt = 0; kt < nt; ++kt) {
        const int k0 = kt * 64;
        if (kt + 1 < nt) STAGE(cur ^ 1, k0 + 64);

        // ---- QK^T: 4 x 16-key blocks from LDS K tile
        f32x4 sf[4];
#pragma unroll
        for (int kb = 0; kb < 4; ++kb) {
            f32x4 s = {0.f, 0.f, 0.f, 0.f};
            const ushort* kl = &Kl[cur][(kb*16 + r) * 128];
#pragma unroll
            for (int c = 0; c < 4; ++c)
                s = __builtin_amdgcn_mfma_f32_16x16x32_bf16(
                    qf[c],
                    *reinterpret_cast<const bf16x8*>(kl + ((4*c + g) ^ swz) * 8),
                    s, 0, 0, 0);
            const int krow = k0 + kb*16 + r;
            if (krow >= seq) { s[0] = -1e30f; s[1] = -1e30f; s[2] = -1e30f; s[3] = -1e30f; }
            sf[kb] = s;
        }
        // ---- online softmax over 64 key cols (rows live in 16-lane groups)
        float pm[4], scl[4], ps[4];
#pragma unroll
        for (int j = 0; j < 4; ++j)
            pm[j] = fmaxf(fmaxf(sf[0][j], sf[1][j]), fmaxf(sf[2][j], sf[3][j]));
#pragma unroll
        for (int off = 1; off < 16; off <<= 1)
#pragma unroll
            for (int j = 0; j < 4; ++j) pm[j] = fmaxf(pm[j], __shfl_xor(pm[j], off));
#pragma unroll
        for (int j = 0; j < 4; ++j) {
            float mn = fmaxf(mrun[j], pm[j]);
            scl[j] = __expf(mrun[j] - mn);
            mrun[j] = mn;
        }
#pragma unroll
        for (int j = 0; j < 4; ++j) {
            sf[0][j] = __expf(sf[0][j] - mrun[j]);
            sf[1][j] = __expf(sf[1][j] - mrun[j]);
            sf[2][j] = __expf(sf[2][j] - mrun[j]);
            sf[3][j] = __expf(sf[3][j] - mrun[j]);
            ps[j] = (sf[0][j] + sf[1][j]) + (sf[2][j] + sf[3][j]);
        }
#pragma unroll
        for (int off = 1; off < 16; off <<= 1)
#pragma unroll
            for (int j = 0; j < 4; ++j) ps[j] += __shfl_xor(ps[j], off);
#pragma unroll
        for (int j = 0; j < 4; ++j) lrun[j] = lrun[j] * scl[j] + ps[j];
#pragma unroll
        for (int f = 0; f < 8; ++f)
#pragma unroll
            for (int j = 0; j < 4; ++j) oacc[f][j] *= scl[j];
        // ---- P -> LDS (bf16), re-read as MFMA A-fragment (per-wave buffer)
#pragma unroll
        for (int kb = 0; kb < 4; ++kb)
#pragma unroll
            for (int j = 0; j < 4; ++j)
                Pl[wave][(g*4 + j)*72 + kb*16 + r] = f2bf(sf[kb][j]);
        bf16x8 pf[2];
        pf[0] = *reinterpret_cast<const bf16x8*>(&Pl[wave][r*72 + g*8]);
        pf[1] = *reinterpret_cast<const bf16x8*>(&Pl[wave][r*72 + 32 + g*8]);
        // ---- PV from LDS V tile [d][k] (swizzled chunks)
#pragma unroll
        for (int db = 0; db < 8; ++db) {
            const ushort* vl = &Vl[cur][(db*16 + r) * 64];
#pragma unroll
            for (int kb2 = 0; kb2 < 2; ++kb2)
                oacc[db] = __builtin_amdgcn_mfma_f32_16x16x32_bf16(
                    pf[kb2],
                    *reinterpret_cast<const bf16x8*>(vl + ((kb2*4 + g) ^ swz) * 8),
                    oacc[db], 0, 0, 0);
        }

        if (kt + 1 < nt) {
            asm volatile("s_waitcnt vmcnt(0)" ::: "memory");
            __syncthreads();
            cur ^= 1;
        }
    }
#undef STAGE

    float inv[4];
#pragma unroll
    for (int j = 0; j < 4; ++j) inv[j] = (lrun[j] > 0.f) ? 1.f / lrun[j] : 0.f;
#pragma unroll
    for (int db = 0; db < 8; ++db)
#pragma unroll
        for (int j = 0; j < 4; ++j)
            attn_out[(size_t)(q0 + g*4 + j) * DIM + n*HD + db*16 + r] =
                f2bf(oacc[db][j] * inv[j]);
}

// ---------------------------------------------------------------------------
extern "C" void kernel_launch(void* const* d_in, const int* in_sizes, int n_in,
                              void* d_out, int out_size, void* d_ws, size_t ws_size,
                              hipStream_t stream)
{
    const float* x    = (const float*)d_in[0];
    const int*   seqL = (const int*)  d_in[1];
    const int*   gsz  = (const int*)  d_in[2];
    const float* fcos = (const float*)d_in[3];
    const float* fsin = (const float*)d_in[4];
    const float* Wq   = (const float*)d_in[5];
    const float* bq   = (const float*)d_in[6];
    const float* Wk   = (const float*)d_in[7];
    const float* bk   = (const float*)d_in[8];
    const float* Wv   = (const float*)d_in[9];
    const float* bv   = (const float*)d_in[10];
    const float* Wo   = (const float*)d_in[11];
    const float* bo   = (const float*)d_in[12];
    const float* gq   = (const float*)d_in[13];
    const float* gk   = (const float*)d_in[14];
    float* out = (float*)d_out;

    char* ws = (char*)d_ws;
    ushort* xb  = (ushort*)ws;                               // 8,257,536 B
    ushort* wb  = xb + (size_t)S_LEN * DIM;                  // 18,874,368 B
    float*  qkv = (float*)(wb + 4*(size_t)DIM*DIM);          // 49,545,216 B
    ushort* q_r = (ushort*)((char*)qkv + (size_t)S_LEN*QKV_N*4); // 8,257,536 B
    ushort* k_r = q_r + (size_t)S_LEN * DIM;                 // 8,257,536 B
    ushort* v_t = k_r + (size_t)S_LEN * DIM;                 // 8,257,536 B
    ushort* ao  = v_t + (size_t)S_LEN * DIM;                 // 8,257,536 B
    // total ws use: ~109.7 MB

    convert_all<<<13248, 256, 0, stream>>>(x, Wq, Wk, Wv, Wo, xb, wb);
    gemm_bt<<<dim3(21, 36), 256, 0, stream>>>(xb, wb, bq, bk, bv, qkv,
                                              S_LEN, QKV_N, DIM);
    normrope<<<S_LEN, 256, 0, stream>>>(qkv, gsz, gq, gk, fcos, fsin, q_r, k_r);
    vtrans<<<dim3(84, 48), 256, 0, stream>>>(qkv, v_t);
    attn_fwd<<<dim3(42, 12), 256, 0, stream>>>(q_r, k_r, v_t, seqL, ao);
    gemm_bt<<<dim3(21, 12), 256, 0, stream>>>(ao, wb + 3*(size_t)DIM*DIM,
                                              bo, bo, bo, out,
                                              S_LEN, DIM, DIM);
}

// Round 6
// 238.033 us; speedup vs baseline: 1.8675x; 1.1087x over previous
//
#include <hip/hip_runtime.h>
#include <hip/hip_bf16.h>
#include <stdint.h>

#define S_LEN 2688
#define DIM   1536
#define NH    12
#define HD    128
#define QKV_N 4608   // 3*DIM

typedef __attribute__((ext_vector_type(8))) short bf16x8;
typedef __attribute__((ext_vector_type(4))) float f32x4;

__device__ inline ushort f2bf(float f) {
    uint32_t u = __float_as_uint(f);
    uint32_t r = (u + 0x7fffu + ((u >> 16) & 1u)) >> 16;
    return (ushort)r;
}

#define GLOAD16(gp, lp) __builtin_amdgcn_global_load_lds( \
    (__attribute__((address_space(1))) const void*)(gp),  \
    (__attribute__((address_space(3))) void*)(lp), 16, 0, 0)

// ---------------------------------------------------------------------------
// 1) fp32 -> bf16 convert: x and the four weight matrices (fused into wb)
// ---------------------------------------------------------------------------
__global__ __launch_bounds__(256) void convert_all(
    const float* __restrict__ x,
    const float* __restrict__ wq, const float* __restrict__ wk,
    const float* __restrict__ wv, const float* __restrict__ wo,
    ushort* __restrict__ xb, ushort* __restrict__ wb)
{
    const size_t NX4 = (size_t)S_LEN * DIM / 4;   // 1,032,192
    const size_t NW4 = (size_t)DIM * DIM / 4;     //   589,824
    size_t i = (size_t)blockIdx.x * 256 + threadIdx.x;
    const float* src; ushort* dst;
    if (i < NX4)            { src = x;  dst = xb; }
    else if (i < NX4+1*NW4) { src = wq; dst = wb;                        i -= NX4; }
    else if (i < NX4+2*NW4) { src = wk; dst = wb + 1*(size_t)DIM*DIM;    i -= NX4+1*NW4; }
    else if (i < NX4+3*NW4) { src = wv; dst = wb + 2*(size_t)DIM*DIM;    i -= NX4+2*NW4; }
    else if (i < NX4+4*NW4) { src = wo; dst = wb + 3*(size_t)DIM*DIM;    i -= NX4+3*NW4; }
    else return;
    float4 v = reinterpret_cast<const float4*>(src)[i];
    ushort4 o = { f2bf(v.x), f2bf(v.y), f2bf(v.z), f2bf(v.w) };
    reinterpret_cast<ushort4*>(dst)[i] = o;
}

// ---------------------------------------------------------------------------
// 2) bf16 GEMM, B^T layout: C[m][n] = sum_k A[m][k]*B[n][k] + bias[n]
//    128x128 tile, BK=64, 4 waves (2x2), 16x16x32 MFMA, global_load_lds w=16
// ---------------------------------------------------------------------------
__global__ __launch_bounds__(256) void gemm_bt(
    const ushort* __restrict__ A, const ushort* __restrict__ B,
    const float* __restrict__ b0, const float* __restrict__ b1,
    const float* __restrict__ b2,
    float* __restrict__ C, int M, int N, int K)
{
    __shared__ ushort At[128 * 64];
    __shared__ ushort Bt[128 * 64];
    const int tid  = threadIdx.x;
    const int wave = tid >> 6, lane = tid & 63;
    const int m0 = blockIdx.x * 128, n0 = blockIdx.y * 128;
    const int wr = wave >> 1, wc = wave & 1;
    const int r = lane & 15, g = lane >> 4;
    const int srow = wave * 8 + (lane >> 3);   // staging row within 32-row chunk
    const int scol = (lane & 7) * 8;           // staging col (8 bf16 = 16B)

    f32x4 acc[4][4] = {};

    for (int k0 = 0; k0 < K; k0 += 64) {
        const ushort* Ag = A + (size_t)m0 * K + k0;
        const ushort* Bg = B + (size_t)n0 * K + k0;
#pragma unroll
        for (int t = 0; t < 4; ++t) {
            GLOAD16(Ag + (size_t)(t*32 + srow) * K + scol, &At[t*2048 + wave*512]);
            GLOAD16(Bg + (size_t)(t*32 + srow) * K + scol, &Bt[t*2048 + wave*512]);
        }
        asm volatile("s_waitcnt vmcnt(0)" ::: "memory");
        __syncthreads();
#pragma unroll
        for (int kk = 0; kk < 2; ++kk) {
            bf16x8 af[4], bfr[4];
#pragma unroll
            for (int i = 0; i < 4; ++i)
                af[i] = *reinterpret_cast<const bf16x8*>(
                    &At[(wr*64 + i*16 + r) * 64 + kk*32 + g*8]);
#pragma unroll
            for (int i = 0; i < 4; ++i)
                bfr[i] = *reinterpret_cast<const bf16x8*>(
                    &Bt[(wc*64 + i*16 + r) * 64 + kk*32 + g*8]);
#pragma unroll
            for (int mi = 0; mi < 4; ++mi)
#pragma unroll
                for (int ni = 0; ni < 4; ++ni)
                    acc[mi][ni] = __builtin_amdgcn_mfma_f32_16x16x32_bf16(
                        af[mi], bfr[ni], acc[mi][ni], 0, 0, 0);
        }
        __syncthreads();
    }

#pragma unroll
    for (int ni = 0; ni < 4; ++ni) {
        int col = n0 + wc*64 + ni*16 + r;
        float bias = (col < DIM) ? b0[col]
                   : (col < 2*DIM) ? b1[col - DIM] : b2[col - 2*DIM];
#pragma unroll
        for (int mi = 0; mi < 4; ++mi) {
            int row = m0 + wr*64 + mi*16 + g*4;
#pragma unroll
            for (int j = 0; j < 4; ++j)
                C[(size_t)(row + j) * N + col] = acc[mi][ni][j] + bias;
        }
    }
}

// ---------------------------------------------------------------------------
// 3) RMS-norm + RoPE for q,k; writes head-major bf16 [n][s][d].
//    1/sqrt(D) attention scale folded into q.
// ---------------------------------------------------------------------------
__global__ __launch_bounds__(256) void normrope(
    const float* __restrict__ qkv, const int* __restrict__ gsz,
    const float* __restrict__ gq, const float* __restrict__ gk,
    const float* __restrict__ fcos, const float* __restrict__ fsin,
    ushort* __restrict__ q_r, ushort* __restrict__ k_r)
{
    const int s   = blockIdx.x;
    const int tid = threadIdx.x;
    const int wave = tid >> 6, lane = tid & 63;
    const float2* qrow = reinterpret_cast<const float2*>(qkv + (size_t)s * QKV_N);
    const float2* krow = reinterpret_cast<const float2*>(qkv + (size_t)s * QKV_N + DIM);

    float2 qv[3], kv[3];
    float sq = 0.f, sk = 0.f;
#pragma unroll
    for (int i = 0; i < 3; ++i) {
        int p = tid + i*256;
        qv[i] = qrow[p]; kv[i] = krow[p];
        sq += qv[i].x*qv[i].x + qv[i].y*qv[i].y;
        sk += kv[i].x*kv[i].x + kv[i].y*kv[i].y;
    }
#pragma unroll
    for (int off = 1; off < 64; off <<= 1) {
        sq += __shfl_xor(sq, off);
        sk += __shfl_xor(sk, off);
    }
    __shared__ float red[4][2];
    if (lane == 0) { red[wave][0] = sq; red[wave][1] = sk; }
    __syncthreads();
    sq = red[0][0] + red[1][0] + red[2][0] + red[3][0];
    sk = red[0][1] + red[1][1] + red[2][1] + red[3][1];
    const float rmsq = rsqrtf(sq * (1.f/DIM) + 1e-6f);
    const float rmsk = rsqrtf(sk * (1.f/DIM) + 1e-6f);

    const int hh = gsz[1], ww = gsz[2];
    const int fidx = s / (hh*ww), rem = s % (hh*ww);
    const int hidx = rem / ww,  widx = rem % ww;
    const float qscale = rmsq * 0.08838834764831845f;  // fold 1/sqrt(128)

#pragma unroll
    for (int i = 0; i < 3; ++i) {
        int p = tid + i*256;               // pair index 0..767
        int c = p & 63, head = p >> 6;
        int coord = (c < 22) ? fidx : (c < 43) ? hidx : widx;
        float cv = fcos[coord*64 + c], sv = fsin[coord*64 + c];
        float2 gqv = reinterpret_cast<const float2*>(gq)[p];
        float2 gkv = reinterpret_cast<const float2*>(gk)[p];
        float a = qv[i].x * qscale * gqv.x, b = qv[i].y * qscale * gqv.y;
        ushort2 qo = { f2bf(a*cv - b*sv), f2bf(a*sv + b*cv) };
        a = kv[i].x * rmsk * gkv.x; b = kv[i].y * rmsk * gkv.y;
        ushort2 ko = { f2bf(a*cv - b*sv), f2bf(a*sv + b*cv) };
        size_t off = ((size_t)head * S_LEN + s) * HD + 2*c;
        *reinterpret_cast<ushort2*>(q_r + off) = qo;
        *reinterpret_cast<ushort2*>(k_r + off) = ko;
    }
}

// ---------------------------------------------------------------------------
// 4) V: fp32 [s][3*DIM..] slice -> bf16 transposed [n][d][s] via LDS tile
// ---------------------------------------------------------------------------
__global__ __launch_bounds__(256) void vtrans(
    const float* __restrict__ qkv, ushort* __restrict__ v_t)
{
    __shared__ ushort tile[32][33];
    const int s0 = blockIdx.x * 32;
    const int d0 = blockIdx.y * 32;     // within 1536
    const int tid = threadIdx.x;
#pragma unroll
    for (int e = 0; e < 4; ++e) {
        int idx = tid + e*256;
        int sl = idx >> 5, dl = idx & 31;
        tile[dl][sl] = f2bf(qkv[(size_t)(s0+sl) * QKV_N + 2*DIM + d0 + dl]);
    }
    __syncthreads();
#pragma unroll
    for (int e = 0; e < 4; ++e) {
        int idx = tid + e*256;
        int dl = idx >> 5, sl = idx & 31;
        int d = d0 + dl;
        int head = d >> 7, dd = d & 127;
        v_t[((size_t)head * HD + dd) * S_LEN + s0 + sl] = tile[dl][sl];
    }
}

// ---------------------------------------------------------------------------
// 5) Flash attention, LDS-staged + SWAPPED operands (T12-style):
//    scores = mfma(K_frag, Q_frag) -> D[key][q]: each lane owns 16 key-scores
//    for one q-row => in-lane softmax reduce (15 ops + 2 shfl_xor).
//    PV swapped: mfma(V_frag, P_frag) -> O[d][q]. Defer-max (T13, THR=8).
//    KVBLK=64, dbuf global_load_lds staging, both-sides XOR chunk swizzle.
// ---------------------------------------------------------------------------
__global__ __launch_bounds__(256) void attn_fwd(
    const ushort* __restrict__ q_r, const ushort* __restrict__ k_r,
    const ushort* __restrict__ v_t, const int* __restrict__ seq_lens,
    ushort* __restrict__ attn_out)
{
    __shared__ ushort Kl[2][64 * 128];   // 2 x 16 KB, [key 0..63][chunk swz]
    __shared__ ushort Vl[2][128 * 64];   // 2 x 16 KB, [d 0..127][chunk swz]
    __shared__ ushort Pl[4][16 * 72];    // per-wave P: [q 0..15][key 0..63], stride 72
    const int tid  = threadIdx.x;
    const int wave = tid >> 6, lane = tid & 63;
    const int n  = blockIdx.y;
    const int q0 = blockIdx.x * 64 + wave * 16;
    const int seq = seq_lens[0];
    const int r = lane & 15, g = lane >> 4;
    const int swz = r & 7;
    const ushort* Qh = q_r + (size_t)n * S_LEN * HD;
    const ushort* Kh = k_r + (size_t)n * S_LEN * HD;
    const ushort* Vh = v_t + (size_t)n * HD * S_LEN;

    // staging indices (per thread): chunk j = t*256+tid
    const int kj_row[4] = { (0*256+tid)>>4, (1*256+tid)>>4, (2*256+tid)>>4, (3*256+tid)>>4 };
    const int kj_w  = tid & 15;
    const int vj_d[4]  = { (0*256+tid)>>3, (1*256+tid)>>3, (2*256+tid)>>3, (3*256+tid)>>3 };
    const int vj_w  = tid & 7;

    bf16x8 qf[4];   // Q[q0+r][c*32+g*8 ..], used as B-fragment (col=q=r)
#pragma unroll
    for (int c = 0; c < 4; ++c)
        qf[c] = *reinterpret_cast<const bf16x8*>(Qh + (size_t)(q0 + r) * HD + c*32 + g*8);

    f32x4 oacc[8] = {};          // oacc[db][j] = O[d=db*16+g*4+j][q=r]
    float mrun = -1e30f, lrun = 0.f;

    const int nt = (seq + 63) >> 6;

#define STAGE(buf, kbase)                                                     \
    do {                                                                      \
        _Pragma("unroll")                                                     \
        for (int t = 0; t < 4; ++t) {                                         \
            int row = kj_row[t];                                              \
            GLOAD16(Kh + (size_t)((kbase) + row) * HD + ((kj_w ^ (row & 7)) * 8), \
                    &Kl[buf][(t*256 + wave*64) * 8]);                         \
        }                                                                     \
        _Pragma("unroll")                                                     \
        for (int t = 0; t < 4; ++t) {                                         \
            int d = vj_d[t];                                                  \
            GLOAD16(Vh + (size_t)d * S_LEN + (kbase) + ((vj_w ^ (d & 7)) * 8), \
                    &Vl[buf][(t*256 + wave*64) * 8]);                         \
        }                                                                     \
    } while (0)

    STAGE(0, 0);
    asm volatile("s_waitcnt vmcnt(0)" ::: "memory");
    __syncthreads();

    int cur = 0;
    for (int kt = 0; kt < nt; ++kt) {
        const int k0 = kt * 64;
        if (kt + 1 < nt) STAGE(cur ^ 1, k0 + 64);

        // ---- QK^T swapped: sf[kb][j] = S[key=k0+kb*16+g*4+j][q=r]
        f32x4 sf[4];
#pragma unroll
        for (int kb = 0; kb < 4; ++kb) {
            f32x4 s = {0.f, 0.f, 0.f, 0.f};
            const ushort* kl = &Kl[cur][(kb*16 + r) * 128];
#pragma unroll
            for (int c = 0; c < 4; ++c)
                s = __builtin_amdgcn_mfma_f32_16x16x32_bf16(
                    *reinterpret_cast<const bf16x8*>(kl + ((4*c + g) ^ swz) * 8),
                    qf[c], s, 0, 0, 0);
            sf[kb] = s;
        }
        if (k0 + 64 > seq) {   // tail mask (never triggers at S=2688, kept for safety)
#pragma unroll
            for (int kb = 0; kb < 4; ++kb)
#pragma unroll
                for (int j = 0; j < 4; ++j)
                    if (k0 + kb*16 + g*4 + j >= seq) sf[kb][j] = -1e30f;
        }
        // ---- in-lane row max over this tile's 16 keys, then across g-groups
        float pm = fmaxf(fmaxf(fmaxf(sf[0][0], sf[0][1]), fmaxf(sf[0][2], sf[0][3])),
                         fmaxf(fmaxf(sf[1][0], sf[1][1]), fmaxf(sf[1][2], sf[1][3])));
        pm = fmaxf(pm, fmaxf(fmaxf(fmaxf(sf[2][0], sf[2][1]), fmaxf(sf[2][2], sf[2][3])),
                             fmaxf(fmaxf(sf[3][0], sf[3][1]), fmaxf(sf[3][2], sf[3][3]))));
        pm = fmaxf(pm, __shfl_xor(pm, 16));
        pm = fmaxf(pm, __shfl_xor(pm, 32));
        // ---- defer-max (T13, THR=8): rescale only when max grew materially
        if (!__all(pm - mrun <= 8.f)) {
            float mn = fmaxf(mrun, pm);
            float scl = __expf(mrun - mn);
            mrun = mn;
            lrun *= scl;
#pragma unroll
            for (int f = 0; f < 8; ++f)
#pragma unroll
                for (int j = 0; j < 4; ++j) oacc[f][j] *= scl;
        }
        // ---- P = exp(S - mrun) (bounded by e^8), in-lane sum + 2 shfl
        float ps = 0.f;
#pragma unroll
        for (int kb = 0; kb < 4; ++kb) {
            float e0 = __expf(sf[kb][0] - mrun), e1 = __expf(sf[kb][1] - mrun);
            float e2 = __expf(sf[kb][2] - mrun), e3 = __expf(sf[kb][3] - mrun);
            sf[kb][0] = e0; sf[kb][1] = e1; sf[kb][2] = e2; sf[kb][3] = e3;
            ps += (e0 + e1) + (e2 + e3);
        }
        ps += __shfl_xor(ps, 16);
        ps += __shfl_xor(ps, 32);
        lrun += ps;
        // ---- P -> LDS: pack 4 bf16 per kb, one b64 write each (addr [q][key])
#pragma unroll
        for (int kb = 0; kb < 4; ++kb) {
            uint2 pkt;
            pkt.x = (uint)f2bf(sf[kb][0]) | ((uint)f2bf(sf[kb][1]) << 16);
            pkt.y = (uint)f2bf(sf[kb][2]) | ((uint)f2bf(sf[kb][3]) << 16);
            *reinterpret_cast<uint2*>(&Pl[wave][r*72 + kb*16 + g*4]) = pkt;
        }
        // P as B-fragment: lane(r,g) needs P[q=r][keys g*8..g*8+7]
        bf16x8 pf[2];
        pf[0] = *reinterpret_cast<const bf16x8*>(&Pl[wave][r*72 + g*8]);
        pf[1] = *reinterpret_cast<const bf16x8*>(&Pl[wave][r*72 + 32 + g*8]);
        // ---- PV swapped: oacc[db] += mfma(V^T_frag, P_frag) -> O[d][q]
#pragma unroll
        for (int db = 0; db < 8; ++db) {
            const ushort* vl = &Vl[cur][(db*16 + r) * 64];
#pragma unroll
            for (int kb2 = 0; kb2 < 2; ++kb2)
                oacc[db] = __builtin_amdgcn_mfma_f32_16x16x32_bf16(
                    *reinterpret_cast<const bf16x8*>(vl + ((kb2*4 + g) ^ swz) * 8),
                    pf[kb2], oacc[db], 0, 0, 0);
        }

        if (kt + 1 < nt) {
            asm volatile("s_waitcnt vmcnt(0)" ::: "memory");
            __syncthreads();
            cur ^= 1;
        }
    }
#undef STAGE

    const float inv = (lrun > 0.f) ? 1.f / lrun : 0.f;
    // row q0+r, cols db*16+g*4+j: pack 4 bf16 -> one b64 store per db
#pragma unroll
    for (int db = 0; db < 8; ++db) {
        uint2 pkt;
        pkt.x = (uint)f2bf(oacc[db][0]*inv) | ((uint)f2bf(oacc[db][1]*inv) << 16);
        pkt.y = (uint)f2bf(oacc[db][2]*inv) | ((uint)f2bf(oacc[db][3]*inv) << 16);
        *reinterpret_cast<uint2*>(
            &attn_out[(size_t)(q0 + r) * DIM + n*HD + db*16 + g*4]) = pkt;
    }
}

// ---------------------------------------------------------------------------
extern "C" void kernel_launch(void* const* d_in, const int* in_sizes, int n_in,
                              void* d_out, int out_size, void* d_ws, size_t ws_size,
                              hipStream_t stream)
{
    const float* x    = (const float*)d_in[0];
    const int*   seqL = (const int*)  d_in[1];
    const int*   gsz  = (const int*)  d_in[2];
    const float* fcos = (const float*)d_in[3];
    const float* fsin = (const float*)d_in[4];
    const float* Wq   = (const float*)d_in[5];
    const float* bq   = (const float*)d_in[6];
    const float* Wk   = (const float*)d_in[7];
    const float* bk   = (const float*)d_in[8];
    const float* Wv   = (const float*)d_in[9];
    const float* bv   = (const float*)d_in[10];
    const float* Wo   = (const float*)d_in[11];
    const float* bo   = (const float*)d_in[12];
    const float* gq   = (const float*)d_in[13];
    const float* gk   = (const float*)d_in[14];
    float* out = (float*)d_out;

    char* ws = (char*)d_ws;
    ushort* xb  = (ushort*)ws;                               // 8,257,536 B
    ushort* wb  = xb + (size_t)S_LEN * DIM;                  // 18,874,368 B
    float*  qkv = (float*)(wb + 4*(size_t)DIM*DIM);          // 49,545,216 B
    ushort* q_r = (ushort*)((char*)qkv + (size_t)S_LEN*QKV_N*4); // 8,257,536 B
    ushort* k_r = q_r + (size_t)S_LEN * DIM;                 // 8,257,536 B
    ushort* v_t = k_r + (size_t)S_LEN * DIM;                 // 8,257,536 B
    ushort* ao  = v_t + (size_t)S_LEN * DIM;                 // 8,257,536 B
    // total ws use: ~109.7 MB

    convert_all<<<13248, 256, 0, stream>>>(x, Wq, Wk, Wv, Wo, xb, wb);
    gemm_bt<<<dim3(21, 36), 256, 0, stream>>>(xb, wb, bq, bk, bv, qkv,
                                              S_LEN, QKV_N, DIM);
    normrope<<<S_LEN, 256, 0, stream>>>(qkv, gsz, gq, gk, fcos, fsin, q_r, k_r);
    vtrans<<<dim3(84, 48), 256, 0, stream>>>(qkv, v_t);
    attn_fwd<<<dim3(42, 12), 256, 0, stream>>>(q_r, k_r, v_t, seqL, ao);
    gemm_bt<<<dim3(21, 12), 256, 0, stream>>>(ao, wb + 3*(size_t)DIM*DIM,
                                              bo, bo, bo, out,
                                              S_LEN, DIM, DIM);
}